// Round 12
// baseline (74.517 us; speedup 1.0000x reference)
//
#include <hip/hip_runtime.h>
#include <math.h>

// B=8, N=1024, D=256, C=8192
#define QROWS 8192
#define DDIM  256
#define CCNT  8192

typedef __attribute__((ext_vector_type(4))) float f32x4;
typedef __attribute__((ext_vector_type(8))) short bf16x8;

__device__ __forceinline__ unsigned short f2bf(float f) {
    unsigned u = __float_as_uint(f);
    u += 0x7fffu + ((u >> 16) & 1u);          // round-to-nearest-even
    return (unsigned short)(u >> 16);
}
__device__ __forceinline__ unsigned u32max(unsigned a, unsigned b) { return a > b ? a : b; }
__device__ __forceinline__ unsigned u32min(unsigned a, unsigned b) { return a < b ? a : b; }

// 2-op monotone key (positives exact-ordered; negatives scrambled but always lose;
// fixup re-scores candidates in exact f32, so only the candidate SET matters):
// key = ((bits(v) ^ 0x80000000) & 0xFFFFFF00) | enc   ->  v_xor + v_bfi
__device__ __forceinline__ unsigned key32(float v, unsigned enc) {
    return ((__float_as_uint(v) ^ 0x80000000u) & 0xFFFFFF00u) | enc;
}

// ---------- merged prep: x -> bf16 ; e -> l2-normalized bf16 ----------
__global__ void k_prep(const float* __restrict__ x, unsigned short* __restrict__ xb,
                       const float* __restrict__ e, unsigned short* __restrict__ eb) {
    const int bid = blockIdx.x;
    if (bid < 1024) {                         // x: 1024 blocks, 8 el/thread
        const int i = (bid * 256 + threadIdx.x) * 8;
        const float4 f0 = *reinterpret_cast<const float4*>(x + i);
        const float4 f1 = *reinterpret_cast<const float4*>(x + i + 4);
        uint4 o;
        o.x = f2bf(f0.x) | ((unsigned)f2bf(f0.y) << 16);
        o.y = f2bf(f0.z) | ((unsigned)f2bf(f0.w) << 16);
        o.z = f2bf(f1.x) | ((unsigned)f2bf(f1.y) << 16);
        o.w = f2bf(f1.z) | ((unsigned)f2bf(f1.w) << 16);
        *reinterpret_cast<uint4*>(xb + i) = o;
    } else {                                  // e: 2048 blocks, 4 rows/block
        const int row  = (bid - 1024) * 4 + (threadIdx.x >> 6);
        const int lane = threadIdx.x & 63;
        const float4 v = *reinterpret_cast<const float4*>(e + (size_t)row * DDIM + lane * 4);
        float s = v.x * v.x + v.y * v.y + v.z * v.z + v.w * v.w;
        #pragma unroll
        for (int off = 1; off < 64; off <<= 1) s += __shfl_xor(s, off);
        const float inv = 1.0f / fmaxf(sqrtf(s), 1e-12f);
        ushort4 o;
        o.x = f2bf(v.x * inv); o.y = f2bf(v.y * inv);
        o.z = f2bf(v.z * inv); o.w = f2bf(v.w * inv);
        *reinterpret_cast<ushort4*>(eb + (size_t)row * DDIM + lane * 4) = o;
    }
}

#define GLOAD_LDS(g, s) \
    __builtin_amdgcn_global_load_lds((const __attribute__((address_space(1))) void*)(g), \
                                     (__attribute__((address_space(3))) void*)(s), 16, 0, 0)

#define SBAR do { asm volatile("" ::: "memory"); __builtin_amdgcn_s_barrier(); \
                  asm volatile("" ::: "memory"); } while (0)
#define WAIT_LGKM(n) do { asm volatile("s_waitcnt lgkmcnt(" #n ")" ::: "memory"); \
                          __builtin_amdgcn_sched_barrier(0); } while (0)
#define WAIT_VM(n) do { asm volatile("s_waitcnt vmcnt(" #n ")" ::: "memory"); \
                        __builtin_amdgcn_sched_barrier(0); } while (0)

// ---------- GEMM: A in registers; B via 8-slot ring; ONE sync point per 4 tiles ----------
// grid 256 = 16 panels x 16 col-splits; block = 8 waves x 64 rows = 512 rows x 512 cols.
// LDS 128 KB: prologue = two A halves (256 rows x 512 B each), then B ring 8 x 16 KB.
// Rows are 512 B = 32 chunks of 16 B; phys chunk = (l&24)|((l&7)^(row&7)), src pre-swizzled.
// Quad loop u=0..3 (tiles 4u..4u+3): WAIT_VM(counted) -> SBAR -> STAGEB next quad ->
// 4 compiler-scheduled tiles (ds_read + MFMA + 2-op-key TILEEND). No per-kk waits.
__launch_bounds__(512, 2)
__global__ void k_gemm(const unsigned short* __restrict__ xb,
                       const unsigned short* __restrict__ eb,
                       unsigned* pout /* aliases d_out */) {
    extern __shared__ char smem[];

    const int tid = threadIdx.x;
    const int w = tid >> 6, l = tid & 63;
    const int lg = l >> 4, lr = l & 15, lr7 = lr & 7;
    const int bid = blockIdx.x;
    const int panel = (bid & 7) * 2 + ((bid >> 3) >> 4);   // XCD x shares 2 panels
    const int split = (bid >> 3) & 15;
    const int n0 = panel * 512, c0 = split * 512;

    // ---- staging constants: thread covers chunk idx = g*512+tid; row=idx>>5, p=tid&31 ----
    const int lchk = (tid & 24) | ((tid & 7) ^ ((tid >> 5) & 7));
    const char* baseA = (const char*)xb + (size_t)(n0 + (tid >> 5)) * 512 + lchk * 16;
    const char* baseB = (const char*)eb + (size_t)(c0 + (tid >> 5)) * 512 + lchk * 16;
    const int wl16 = w * 1024;                 // wave-uniform LDS base

#define STAGE_AHALF(h) do { _Pragma("unroll") for (int g_ = 0; g_ < 16; ++g_)              \
    GLOAD_LDS(baseA + (h) * 131072 + g_ * 8192, smem + g_ * 8192 + wl16); } while (0)
#define STAGEB(t) do { _Pragma("unroll") for (int g_ = 0; g_ < 2; ++g_)                    \
    GLOAD_LDS(baseB + (size_t)(t) * 16384 + g_ * 8192,                                     \
              smem + ((t) & 7) * 16384 + g_ * 8192 + wl16); } while (0)

    // ---- A fragments: 64 rows x 256 K per wave ----
    bf16x8 aF[4][8];
#define READA() do { _Pragma("unroll") for (int mi_ = 0; mi_ < 4; ++mi_)                   \
    _Pragma("unroll") for (int kk_ = 0; kk_ < 8; ++kk_) {                                  \
        const int lc_ = kk_ * 4 + lg;                                                      \
        const int ph_ = (lc_ & 24) | ((lc_ & 7) ^ lr7);                                    \
        aF[mi_][kk_] = *reinterpret_cast<const bf16x8*>(                                   \
            smem + ((w & 3) * 64 + mi_ * 16 + lr) * 512 + ph_ * 16); } } while (0)

    // ---- prologue: two 128-KB A halves, 4 waves read each half in parallel ----
    STAGE_AHALF(0);
    WAIT_VM(0); SBAR;
    if (w < 4) READA();                       // waves 0-3 own rows in half 0
    WAIT_LGKM(0); SBAR;                       // readers drained before overwrite
    STAGE_AHALF(1);
    WAIT_VM(0); SBAR;
    if (w >= 4) READA();                      // waves 4-7 own rows in half 1
    WAIT_LGKM(0); SBAR;
    STAGEB(0); STAGEB(1); STAGEB(2); STAGEB(3);
    STAGEB(4); STAGEB(5); STAGEB(6); STAGEB(7);          // 16 loads in flight

    // ---- main loop state ----
    const f32x4 zf4 = {0.f, 0.f, 0.f, 0.f};
    unsigned rk1[16], rk2[16];
    #pragma unroll
    for (int i = 0; i < 16; ++i) { rk1[i] = 0u; rk2[i] = 0u; }

// One tile: 8 kk x {2 ds_read_b128, 8 MFMA}; kk=0 uses zero-C (no acc zeroing);
// TILEEND: 2-op keys + max/min ladder into running per-thread top-2.
#define TILE(t) do {                                                                       \
    const char* sb_ = smem + ((t) & 7) * 16384;                                            \
    f32x4 ac0_[4], ac1_[4];                                                                \
    {                                                                                      \
        const int ph0_ = ((lg & 24) | ((lg & 7) ^ lr7)) * 16;                              \
        const bf16x8 b0_ = *reinterpret_cast<const bf16x8*>(sb_ + lr * 512 + ph0_);        \
        const bf16x8 b1_ = *reinterpret_cast<const bf16x8*>(sb_ + (16 + lr) * 512 + ph0_); \
        _Pragma("unroll") for (int mi_ = 0; mi_ < 4; ++mi_) {                              \
            ac0_[mi_] = __builtin_amdgcn_mfma_f32_16x16x32_bf16(aF[mi_][0], b0_, zf4, 0, 0, 0); \
            ac1_[mi_] = __builtin_amdgcn_mfma_f32_16x16x32_bf16(aF[mi_][0], b1_, zf4, 0, 0, 0); \
        }                                                                                  \
    }                                                                                      \
    _Pragma("unroll") for (int kk_ = 1; kk_ < 8; ++kk_) {                                  \
        const int lc_ = kk_ * 4 + lg;                                                      \
        const int ph_ = ((lc_ & 24) | ((lc_ & 7) ^ lr7)) * 16;                             \
        const bf16x8 b0_ = *reinterpret_cast<const bf16x8*>(sb_ + lr * 512 + ph_);         \
        const bf16x8 b1_ = *reinterpret_cast<const bf16x8*>(sb_ + (16 + lr) * 512 + ph_);  \
        _Pragma("unroll") for (int mi_ = 0; mi_ < 4; ++mi_) {                              \
            ac0_[mi_] = __builtin_amdgcn_mfma_f32_16x16x32_bf16(aF[mi_][kk_], b0_, ac0_[mi_], 0, 0, 0); \
            ac1_[mi_] = __builtin_amdgcn_mfma_f32_16x16x32_bf16(aF[mi_][kk_], b1_, ac1_[mi_], 0, 0, 0); \
        }                                                                                  \
    }                                                                                      \
    const unsigned encb_ = (unsigned)(255 - ((t) & 7) * 32) - (unsigned)lr;                \
    _Pragma("unroll") for (int mi_ = 0; mi_ < 4; ++mi_)                                    \
        _Pragma("unroll") for (int rr_ = 0; rr_ < 4; ++rr_) {                              \
            const unsigned q0_ = key32(ac0_[mi_][rr_], encb_);                             \
            const unsigned q1_ = key32(ac1_[mi_][rr_], encb_ - 16u);                       \
            const unsigned m01_ = u32max(q0_, q1_), n01_ = u32min(q0_, q1_);               \
            const int i_ = mi_ * 4 + rr_;                                                  \
            const unsigned lo_ = u32min(rk1[i_], m01_);                                    \
            rk1[i_] = u32max(rk1[i_], m01_);                                               \
            rk2[i_] = u32max(rk2[i_], u32max(n01_, lo_));                                  \
        }                                                                                  \
} while (0)

// flush: merge the 16 lr-lanes' running top-2, store this half's partials, reset
#define FLUSH(half) do {                                                                   \
    _Pragma("unroll") for (int i_ = 0; i_ < 16; ++i_) {                                    \
        unsigned t1_ = rk1[i_], t2_ = rk2[i_];                                             \
        _Pragma("unroll") for (int off_ = 1; off_ < 16; off_ <<= 1) {                      \
            const unsigned o1_ = __shfl_xor(t1_, off_);                                    \
            const unsigned o2_ = __shfl_xor(t2_, off_);                                    \
            const unsigned n1_ = u32max(t1_, o1_), lo_ = u32min(t1_, o1_);                 \
            t2_ = u32max(u32max(t2_, o2_), lo_);                                           \
            t1_ = n1_;                                                                     \
        }                                                                                  \
        if (lr == 0) {                                                                     \
            const int row_ = n0 + w * 64 + (i_ >> 2) * 16 + lg * 4 + (i_ & 3);             \
            uint2 o_; o_.x = t1_; o_.y = t2_;                                              \
            *reinterpret_cast<uint2*>(pout + (size_t)row_ * 256 + split * 4 + (half) * 2) = o_; \
        }                                                                                  \
        rk1[i_] = 0u; rk2[i_] = 0u;                                                        \
    }                                                                                      \
} while (0)

    // ---- 4 quads of tiles; one WAIT_VM + SBAR per quad ----
    // vmcnt FIFO trace (per wave, 2 loads/tile):
    //  u0 entry: tiles 0-7 out (16) -> VM(8) retires 0-3. SBAR. no stage (slots full).
    //  u1 entry: tiles 4-7 out (8)  -> VM(0). SBAR. STAGEB 8-11 (slots 0-3: all waves
    //            passed SBAR(u1) after reading tiles 0-3 -> WAR safe). FLUSH(0) stores
    //            enter queue AFTER these loads.
    //  u2 entry: loads 8-11 (8) + 16 stores -> VM(16) retires the 8 loads. SBAR.
    //            STAGEB 12-15 (slots 4-7, WAR safe via SBAR(u2)).
    //  u3 entry: 16 stores (old) + loads 12-15 -> VM(0) (all ~10k cyc old, free).
    #pragma unroll 1
    for (int u = 0; u < 4; ++u) {
        if (u == 0)      { WAIT_VM(8); }
        else if (u == 1) { WAIT_VM(0); }
        else if (u == 2) { WAIT_VM(16); }
        else             { WAIT_VM(0); }
        SBAR;
        if (u == 1) { STAGEB(8); STAGEB(9); STAGEB(10); STAGEB(11); }
        if (u == 2) { STAGEB(12); STAGEB(13); STAGEB(14); STAGEB(15); }
        TILE(4 * u);
        TILE(4 * u + 1);
        TILE(4 * u + 2);
        TILE(4 * u + 3);
        if (u == 1) FLUSH(0);                 // first 256-col half done (tiles 0-7)
        if (u == 3) FLUSH(1);                 // second half
    }
#undef STAGE_AHALF
#undef STAGEB
#undef READA
#undef TILE
#undef FLUSH
}

// ---------- fixup: global top-4 of 64 keys -> exact f32 -> argmax + gather ----------
__global__ void k_fixup(const unsigned* pk,  // == (u32*)d_out, intentionally no restrict
                        const float* __restrict__ x, const float* __restrict__ e,
                        float* out) {
    const int row = blockIdx.x * 4 + (threadIdx.x >> 6);
    const int t   = threadIdx.x & 63;   // t<32: half-split partial holder (256 cols each)
    unsigned long long kk0 = 0ull, kk1 = 0ull;
    if (t < 32) {
        const uint2 kv = reinterpret_cast<const uint2*>(pk + (size_t)row * 256)[t];
        const int col0 = t * 256 + 255 - (int)(kv.x & 255u);
        kk0 = ((unsigned long long)(kv.x & 0xFFFFFF00u) << 32) | (unsigned)(~col0);
        const int col1 = t * 256 + 255 - (int)(kv.y & 255u);
        kk1 = ((unsigned long long)(kv.y & 0xFFFFFF00u) << 32) | (unsigned)(~col1);
    }

    int cand[4];
    #pragma unroll
    for (int p = 0; p < 4; ++p) {
        unsigned long long m = kk0 > kk1 ? kk0 : kk1;
        #pragma unroll
        for (int off = 1; off < 64; off <<= 1) {
            const unsigned long long o = __shfl_xor(m, off);
            if (o > m) m = o;
        }
        cand[p] = (int)(~(unsigned)m) & (CCNT - 1);
        if (kk0 == m) kk0 = 0ull;
        if (kk1 == m) kk1 = 0ull;
    }

    const float4 xv = *reinterpret_cast<const float4*>(x + (size_t)row * DDIM + t * 4);
    float best = -INFINITY; int bc = 0x7fffffff;
    #pragma unroll
    for (int p = 0; p < 4; ++p) {
        const int c = cand[p];
        const float4 ev = *reinterpret_cast<const float4*>(e + (size_t)c * DDIM + t * 4);
        float d  = xv.x * ev.x + xv.y * ev.y + xv.z * ev.z + xv.w * ev.w;
        float ss = ev.x * ev.x + ev.y * ev.y + ev.z * ev.z + ev.w * ev.w;
        #pragma unroll
        for (int off = 1; off < 64; off <<= 1) {
            d  += __shfl_xor(d, off);
            ss += __shfl_xor(ss, off);
        }
        const float v = d * (1.0f / fmaxf(sqrtf(ss), 1e-12f));
        if (v > best || (v == best && c < bc)) { best = v; bc = c; }
    }

    if (t == 0) out[(size_t)QROWS * DDIM + row] = (float)bc;
    const float4 q = *reinterpret_cast<const float4*>(e + (size_t)bc * DDIM + t * 4);
    *reinterpret_cast<float4*>(out + (size_t)row * DDIM + t * 4) = q; // overwrites this row's partials only
}

extern "C" void kernel_launch(void* const* d_in, const int* in_sizes, int n_in,
                              void* d_out, int out_size, void* d_ws, size_t ws_size,
                              hipStream_t stream) {
    const float* x = (const float*)d_in[0];
    const float* e = (const float*)d_in[1];
    float* out = (float*)d_out;
    char* ws = (char*)d_ws;

    unsigned short* xb = (unsigned short*)ws;                             // 4 MB
    unsigned short* eb = (unsigned short*)(ws + (size_t)4 * 1024 * 1024); // 4 MB

    hipFuncSetAttribute(reinterpret_cast<const void*>(k_gemm),
                        hipFuncAttributeMaxDynamicSharedMemorySize, 131072);

    k_prep<<<3072, 256, 0, stream>>>(x, xb, e, eb);
    k_gemm<<<256, 512, 131072, stream>>>(xb, eb, (unsigned*)d_out);
    k_fixup<<<QROWS / 4, 256, 0, stream>>>((const unsigned*)d_out, x, e, out);
}

// Round 13
// 62.457 us; speedup vs baseline: 1.1931x; 1.1931x over previous
//
#include <hip/hip_runtime.h>
#include <math.h>

// B=8, N=1024, D=256, C=8192
#define QROWS 8192
#define DDIM  256
#define CCNT  8192

typedef __attribute__((ext_vector_type(4))) float f32x4;
typedef __attribute__((ext_vector_type(8))) short bf16x8;

__device__ __forceinline__ unsigned short f2bf(float f) {
    unsigned u = __float_as_uint(f);
    u += 0x7fffu + ((u >> 16) & 1u);          // round-to-nearest-even
    return (unsigned short)(u >> 16);
}
__device__ __forceinline__ unsigned u32max(unsigned a, unsigned b) { return a > b ? a : b; }
__device__ __forceinline__ unsigned u32min(unsigned a, unsigned b) { return a < b ? a : b; }

// 2-op monotone key (positives exact-ordered; negatives scrambled but always lose;
// fixup re-scores candidates in exact f32, so only the candidate SET matters):
// key = ((bits(v) ^ 0x80000000) & 0xFFFFFF00) | enc   ->  v_xor + v_bfi
__device__ __forceinline__ unsigned key32(float v, unsigned enc) {
    return ((__float_as_uint(v) ^ 0x80000000u) & 0xFFFFFF00u) | enc;
}

// ---------- merged prep: x -> bf16 ; e -> l2-normalized bf16 ----------
__global__ void k_prep(const float* __restrict__ x, unsigned short* __restrict__ xb,
                       const float* __restrict__ e, unsigned short* __restrict__ eb) {
    const int bid = blockIdx.x;
    if (bid < 1024) {                         // x: 1024 blocks, 8 el/thread
        const int i = (bid * 256 + threadIdx.x) * 8;
        const float4 f0 = *reinterpret_cast<const float4*>(x + i);
        const float4 f1 = *reinterpret_cast<const float4*>(x + i + 4);
        uint4 o;
        o.x = f2bf(f0.x) | ((unsigned)f2bf(f0.y) << 16);
        o.y = f2bf(f0.z) | ((unsigned)f2bf(f0.w) << 16);
        o.z = f2bf(f1.x) | ((unsigned)f2bf(f1.y) << 16);
        o.w = f2bf(f1.z) | ((unsigned)f2bf(f1.w) << 16);
        *reinterpret_cast<uint4*>(xb + i) = o;
    } else {                                  // e: 2048 blocks, 4 rows/block
        const int row  = (bid - 1024) * 4 + (threadIdx.x >> 6);
        const int lane = threadIdx.x & 63;
        const float4 v = *reinterpret_cast<const float4*>(e + (size_t)row * DDIM + lane * 4);
        float s = v.x * v.x + v.y * v.y + v.z * v.z + v.w * v.w;
        #pragma unroll
        for (int off = 1; off < 64; off <<= 1) s += __shfl_xor(s, off);
        const float inv = 1.0f / fmaxf(sqrtf(s), 1e-12f);
        ushort4 o;
        o.x = f2bf(v.x * inv); o.y = f2bf(v.y * inv);
        o.z = f2bf(v.z * inv); o.w = f2bf(v.w * inv);
        *reinterpret_cast<ushort4*>(eb + (size_t)row * DDIM + lane * 4) = o;
    }
}

#define GLOAD_LDS(g, s) \
    __builtin_amdgcn_global_load_lds((const __attribute__((address_space(1))) void*)(g), \
                                     (__attribute__((address_space(3))) void*)(s), 16, 0, 0)

#define SBAR do { asm volatile("" ::: "memory"); __builtin_amdgcn_s_barrier(); \
                  asm volatile("" ::: "memory"); } while (0)
#define WAIT_LGKM(n) do { asm volatile("s_waitcnt lgkmcnt(" #n ")" ::: "memory"); \
                          __builtin_amdgcn_sched_barrier(0); } while (0)
#define WAIT_VM(n) do { asm volatile("s_waitcnt vmcnt(" #n ")" ::: "memory"); \
                        __builtin_amdgcn_sched_barrier(0); } while (0)

// ---------- GEMM: A in registers; B via 8-slot ring; one sync point per 2 tiles ----------
// grid 256 = 16 panels x 16 col-splits; block = 8 waves x 64 rows = 512 rows x 512 cols.
// LDS 128 KB: prologue = two A halves (256 rows x 512 B each), then B ring 8 x 16 KB.
// Rows are 512 B = 32 chunks of 16 B; phys chunk = (l&24)|((l&7)^(row&7)), src pre-swizzled.
// r11-proven pacing: pair loop u=0..7, WAIT_VM(8/4/0) -> SBAR -> STAGEB 2 tiles -> 2 TILEs.
// r12-proven epilogue: zero-C kk=0, 2-op keys, max3 top-2 update.
__launch_bounds__(512, 2)
__global__ void k_gemm(const unsigned short* __restrict__ xb,
                       const unsigned short* __restrict__ eb,
                       unsigned* pout /* aliases d_out */) {
    extern __shared__ char smem[];

    const int tid = threadIdx.x;
    const int w = tid >> 6, l = tid & 63;
    const int lg = l >> 4, lr = l & 15, lr7 = lr & 7;
    const int bid = blockIdx.x;
    const int panel = (bid & 7) * 2 + ((bid >> 3) >> 4);   // XCD x shares 2 panels
    const int split = (bid >> 3) & 15;
    const int n0 = panel * 512, c0 = split * 512;

    // ---- staging constants: thread covers chunk idx = g*512+tid; row=idx>>5, p=tid&31 ----
    const int lchk = (tid & 24) | ((tid & 7) ^ ((tid >> 5) & 7));
    const char* baseA = (const char*)xb + (size_t)(n0 + (tid >> 5)) * 512 + lchk * 16;
    const char* baseB = (const char*)eb + (size_t)(c0 + (tid >> 5)) * 512 + lchk * 16;
    const int wl16 = w * 1024;                 // wave-uniform LDS base

#define STAGE_AHALF(h) do { _Pragma("unroll") for (int g_ = 0; g_ < 16; ++g_)              \
    GLOAD_LDS(baseA + (h) * 131072 + g_ * 8192, smem + g_ * 8192 + wl16); } while (0)
#define STAGEB(t) do { _Pragma("unroll") for (int g_ = 0; g_ < 2; ++g_)                    \
    GLOAD_LDS(baseB + (size_t)(t) * 16384 + g_ * 8192,                                     \
              smem + ((t) & 7) * 16384 + g_ * 8192 + wl16); } while (0)

    // ---- A fragments: 64 rows x 256 K per wave = 128 VGPR ----
    bf16x8 aF[4][8];
#define READA() do { _Pragma("unroll") for (int mi_ = 0; mi_ < 4; ++mi_)                   \
    _Pragma("unroll") for (int kk_ = 0; kk_ < 8; ++kk_) {                                  \
        const int lc_ = kk_ * 4 + lg;                                                      \
        const int ph_ = (lc_ & 24) | ((lc_ & 7) ^ lr7);                                    \
        aF[mi_][kk_] = *reinterpret_cast<const bf16x8*>(                                   \
            smem + ((w & 3) * 64 + mi_ * 16 + lr) * 512 + ph_ * 16); } } while (0)

    // ---- prologue: two 128-KB A halves, 4 waves read each half in parallel ----
    STAGE_AHALF(0);
    WAIT_VM(0); SBAR;
    if (w < 4) READA();                       // waves 0-3 own rows in half 0
    WAIT_LGKM(0); SBAR;                       // readers drained before overwrite
    STAGE_AHALF(1);
    WAIT_VM(0); SBAR;
    if (w >= 4) READA();                      // waves 4-7 own rows in half 1
    WAIT_LGKM(0); SBAR;
    STAGEB(0); STAGEB(1); STAGEB(2); STAGEB(3); STAGEB(4); STAGEB(5);   // 12 loads in flight

    // ---- main loop state ----
    const f32x4 zf4 = {0.f, 0.f, 0.f, 0.f};
    unsigned rk1[16], rk2[16];
    #pragma unroll
    for (int i = 0; i < 16; ++i) { rk1[i] = 0u; rk2[i] = 0u; }

// One tile: 8 kk x {2 ds_read_b128, 8 MFMA}; kk=0 uses zero-C (no acc zeroing);
// TILEEND: 2-op keys + max/min/max3 ladder into running per-thread top-2.
#define TILE(t) do {                                                                       \
    const char* sb_ = smem + ((t) & 7) * 16384;                                            \
    f32x4 ac0_[4], ac1_[4];                                                                \
    {                                                                                      \
        const int ph0_ = ((lg & 24) | ((lg & 7) ^ lr7)) * 16;                              \
        const bf16x8 b0_ = *reinterpret_cast<const bf16x8*>(sb_ + lr * 512 + ph0_);        \
        const bf16x8 b1_ = *reinterpret_cast<const bf16x8*>(sb_ + (16 + lr) * 512 + ph0_); \
        _Pragma("unroll") for (int mi_ = 0; mi_ < 4; ++mi_) {                              \
            ac0_[mi_] = __builtin_amdgcn_mfma_f32_16x16x32_bf16(aF[mi_][0], b0_, zf4, 0, 0, 0); \
            ac1_[mi_] = __builtin_amdgcn_mfma_f32_16x16x32_bf16(aF[mi_][0], b1_, zf4, 0, 0, 0); \
        }                                                                                  \
    }                                                                                      \
    _Pragma("unroll") for (int kk_ = 1; kk_ < 8; ++kk_) {                                  \
        const int lc_ = kk_ * 4 + lg;                                                      \
        const int ph_ = ((lc_ & 24) | ((lc_ & 7) ^ lr7)) * 16;                             \
        const bf16x8 b0_ = *reinterpret_cast<const bf16x8*>(sb_ + lr * 512 + ph_);         \
        const bf16x8 b1_ = *reinterpret_cast<const bf16x8*>(sb_ + (16 + lr) * 512 + ph_);  \
        _Pragma("unroll") for (int mi_ = 0; mi_ < 4; ++mi_) {                              \
            ac0_[mi_] = __builtin_amdgcn_mfma_f32_16x16x32_bf16(aF[mi_][kk_], b0_, ac0_[mi_], 0, 0, 0); \
            ac1_[mi_] = __builtin_amdgcn_mfma_f32_16x16x32_bf16(aF[mi_][kk_], b1_, ac1_[mi_], 0, 0, 0); \
        }                                                                                  \
    }                                                                                      \
    const unsigned encb_ = (unsigned)(255 - ((t) & 7) * 32) - (unsigned)lr;                \
    _Pragma("unroll") for (int mi_ = 0; mi_ < 4; ++mi_)                                    \
        _Pragma("unroll") for (int rr_ = 0; rr_ < 4; ++rr_) {                              \
            const unsigned q0_ = key32(ac0_[mi_][rr_], encb_);                             \
            const unsigned q1_ = key32(ac1_[mi_][rr_], encb_ - 16u);                       \
            const unsigned m01_ = u32max(q0_, q1_), n01_ = u32min(q0_, q1_);               \
            const int i_ = mi_ * 4 + rr_;                                                  \
            const unsigned lo_ = u32min(rk1[i_], m01_);                                    \
            rk1[i_] = u32max(rk1[i_], m01_);                                               \
            rk2[i_] = u32max(rk2[i_], u32max(n01_, lo_));                                  \
        }                                                                                  \
} while (0)

// flush: merge the 16 lr-lanes' running top-2, store this half's partials, reset
#define FLUSH(half) do {                                                                   \
    _Pragma("unroll") for (int i_ = 0; i_ < 16; ++i_) {                                    \
        unsigned t1_ = rk1[i_], t2_ = rk2[i_];                                             \
        _Pragma("unroll") for (int off_ = 1; off_ < 16; off_ <<= 1) {                      \
            const unsigned o1_ = __shfl_xor(t1_, off_);                                    \
            const unsigned o2_ = __shfl_xor(t2_, off_);                                    \
            const unsigned n1_ = u32max(t1_, o1_), lo_ = u32min(t1_, o1_);                 \
            t2_ = u32max(u32max(t2_, o2_), lo_);                                           \
            t1_ = n1_;                                                                     \
        }                                                                                  \
        if (lr == 0) {                                                                     \
            const int row_ = n0 + w * 64 + (i_ >> 2) * 16 + lg * 4 + (i_ & 3);             \
            uint2 o_; o_.x = t1_; o_.y = t2_;                                              \
            *reinterpret_cast<uint2*>(pout + (size_t)row_ * 256 + split * 4 + (half) * 2) = o_; \
        }                                                                                  \
        rk1[i_] = 0u; rk2[i_] = 0u;                                                        \
    }                                                                                      \
} while (0)

    // ---- 8 pairs of tiles; one WAIT_VM + SBAR per pair (r11-proven pacing) ----
    #pragma unroll 1
    for (int u = 0; u < 8; ++u) {
        if (u < 6)       { WAIT_VM(8); }
        else if (u == 6) { WAIT_VM(4); }
        else             { WAIT_VM(0); }
        SBAR;
        if (u < 5) { STAGEB(2 * u + 6); STAGEB(2 * u + 7); }
        TILE(2 * u);
        TILE(2 * u + 1);
        if (u == 3) FLUSH(0);                 // first 256-col half done (tiles 0-7)
        if (u == 7) FLUSH(1);                 // second half
    }
#undef STAGE_AHALF
#undef STAGEB
#undef READA
#undef TILE
#undef FLUSH
}

// ---------- fixup: global top-4 of 64 keys -> exact f32 -> argmax + gather ----------
__global__ void k_fixup(const unsigned* pk,  // == (u32*)d_out, intentionally no restrict
                        const float* __restrict__ x, const float* __restrict__ e,
                        float* out) {
    const int row = blockIdx.x * 4 + (threadIdx.x >> 6);
    const int t   = threadIdx.x & 63;   // t<32: half-split partial holder (256 cols each)
    unsigned long long kk0 = 0ull, kk1 = 0ull;
    if (t < 32) {
        const uint2 kv = reinterpret_cast<const uint2*>(pk + (size_t)row * 256)[t];
        const int col0 = t * 256 + 255 - (int)(kv.x & 255u);
        kk0 = ((unsigned long long)(kv.x & 0xFFFFFF00u) << 32) | (unsigned)(~col0);
        const int col1 = t * 256 + 255 - (int)(kv.y & 255u);
        kk1 = ((unsigned long long)(kv.y & 0xFFFFFF00u) << 32) | (unsigned)(~col1);
    }

    int cand[4];
    #pragma unroll
    for (int p = 0; p < 4; ++p) {
        unsigned long long m = kk0 > kk1 ? kk0 : kk1;
        #pragma unroll
        for (int off = 1; off < 64; off <<= 1) {
            const unsigned long long o = __shfl_xor(m, off);
            if (o > m) m = o;
        }
        cand[p] = (int)(~(unsigned)m) & (CCNT - 1);
        if (kk0 == m) kk0 = 0ull;
        if (kk1 == m) kk1 = 0ull;
    }

    const float4 xv = *reinterpret_cast<const float4*>(x + (size_t)row * DDIM + t * 4);
    float best = -INFINITY; int bc = 0x7fffffff;
    #pragma unroll
    for (int p = 0; p < 4; ++p) {
        const int c = cand[p];
        const float4 ev = *reinterpret_cast<const float4*>(e + (size_t)c * DDIM + t * 4);
        float d  = xv.x * ev.x + xv.y * ev.y + xv.z * ev.z + xv.w * ev.w;
        float ss = ev.x * ev.x + ev.y * ev.y + ev.z * ev.z + ev.w * ev.w;
        #pragma unroll
        for (int off = 1; off < 64; off <<= 1) {
            d  += __shfl_xor(d, off);
            ss += __shfl_xor(ss, off);
        }
        const float v = d * (1.0f / fmaxf(sqrtf(ss), 1e-12f));
        if (v > best || (v == best && c < bc)) { best = v; bc = c; }
    }

    if (t == 0) out[(size_t)QROWS * DDIM + row] = (float)bc;
    const float4 q = *reinterpret_cast<const float4*>(e + (size_t)bc * DDIM + t * 4);
    *reinterpret_cast<float4*>(out + (size_t)row * DDIM + t * 4) = q; // overwrites this row's partials only
}

extern "C" void kernel_launch(void* const* d_in, const int* in_sizes, int n_in,
                              void* d_out, int out_size, void* d_ws, size_t ws_size,
                              hipStream_t stream) {
    const float* x = (const float*)d_in[0];
    const float* e = (const float*)d_in[1];
    float* out = (float*)d_out;
    char* ws = (char*)d_ws;

    unsigned short* xb = (unsigned short*)ws;                             // 4 MB
    unsigned short* eb = (unsigned short*)(ws + (size_t)4 * 1024 * 1024); // 4 MB

    hipFuncSetAttribute(reinterpret_cast<const void*>(k_gemm),
                        hipFuncAttributeMaxDynamicSharedMemorySize, 131072);

    k_prep<<<3072, 256, 0, stream>>>(x, xb, e, eb);
    k_gemm<<<256, 512, 131072, stream>>>(xb, eb, (unsigned*)d_out);
    k_fixup<<<QROWS / 4, 256, 0, stream>>>((const unsigned*)d_out, x, e, out);
}

// Round 14
// 61.095 us; speedup vs baseline: 1.2197x; 1.0223x over previous
//
#include <hip/hip_runtime.h>
#include <math.h>

// B=8, N=1024, D=256, C=8192
#define QROWS 8192
#define DDIM  256
#define CCNT  8192

typedef __attribute__((ext_vector_type(4))) float f32x4;
typedef __attribute__((ext_vector_type(8))) short bf16x8;

__device__ __forceinline__ unsigned short f2bf(float f) {
    unsigned u = __float_as_uint(f);
    u += 0x7fffu + ((u >> 16) & 1u);          // round-to-nearest-even
    return (unsigned short)(u >> 16);
}
__device__ __forceinline__ unsigned u32max(unsigned a, unsigned b) { return a > b ? a : b; }
__device__ __forceinline__ unsigned u32min(unsigned a, unsigned b) { return a < b ? a : b; }

// 2-op monotone key (positives exact-ordered; negatives scrambled but always lose;
// fixup re-scores candidates in exact f32, so only the candidate SET matters)
__device__ __forceinline__ unsigned key32(float v, unsigned enc) {
    return ((__float_as_uint(v) ^ 0x80000000u) & 0xFFFFFF00u) | enc;
}

// ---------- merged prep: x -> bf16 ; e -> l2-normalized bf16 ----------
__global__ void k_prep(const float* __restrict__ x, unsigned short* __restrict__ xb,
                       const float* __restrict__ e, unsigned short* __restrict__ eb) {
    const int bid = blockIdx.x;
    if (bid < 1024) {                         // x: 1024 blocks, 8 el/thread
        const int i = (bid * 256 + threadIdx.x) * 8;
        const float4 f0 = *reinterpret_cast<const float4*>(x + i);
        const float4 f1 = *reinterpret_cast<const float4*>(x + i + 4);
        uint4 o;
        o.x = f2bf(f0.x) | ((unsigned)f2bf(f0.y) << 16);
        o.y = f2bf(f0.z) | ((unsigned)f2bf(f0.w) << 16);
        o.z = f2bf(f1.x) | ((unsigned)f2bf(f1.y) << 16);
        o.w = f2bf(f1.z) | ((unsigned)f2bf(f1.w) << 16);
        *reinterpret_cast<uint4*>(xb + i) = o;
    } else {                                  // e: 2048 blocks, 4 rows/block
        const int row  = (bid - 1024) * 4 + (threadIdx.x >> 6);
        const int lane = threadIdx.x & 63;
        const float4 v = *reinterpret_cast<const float4*>(e + (size_t)row * DDIM + lane * 4);
        float s = v.x * v.x + v.y * v.y + v.z * v.z + v.w * v.w;
        #pragma unroll
        for (int off = 1; off < 64; off <<= 1) s += __shfl_xor(s, off);
        const float inv = 1.0f / fmaxf(sqrtf(s), 1e-12f);
        ushort4 o;
        o.x = f2bf(v.x * inv); o.y = f2bf(v.y * inv);
        o.z = f2bf(v.z * inv); o.w = f2bf(v.w * inv);
        *reinterpret_cast<ushort4*>(eb + (size_t)row * DDIM + lane * 4) = o;
    }
}

#define GLOAD_LDS(g, s) \
    __builtin_amdgcn_global_load_lds((const __attribute__((address_space(1))) void*)(g), \
                                     (__attribute__((address_space(3))) void*)(s), 16, 0, 0)

#define SBAR do { asm volatile("" ::: "memory"); __builtin_amdgcn_s_barrier(); \
                  asm volatile("" ::: "memory"); } while (0)
#define WAIT_LGKM(n) do { asm volatile("s_waitcnt lgkmcnt(" #n ")" ::: "memory"); \
                          __builtin_amdgcn_sched_barrier(0); } while (0)
#define WAIT_VM(n) do { asm volatile("s_waitcnt vmcnt(" #n ")" ::: "memory"); \
                        __builtin_amdgcn_sched_barrier(0); } while (0)

// ---------- GEMM: 4 waves/block, 2 blocks/CU; A in regs; B via 8x8KB ring ----------
// grid 512 = 32 panels (256 rows) x 16 splits (512 cols); block = 4 waves x 64 rows.
// LDS 64 KB: A prologue staged in 2 x 64 KB rounds through the ring space, then
// B ring 8 slots x 8 KB (16 cols x 512 B). Rows 512 B = 32 chunks of 16 B;
// phys chunk = (p&24)|((p&7)^(row&7)), source pre-swizzled, LDS dest linear.
// Pair pacing (r11-proven): u=0..15, WAIT_VM(8/4/0) -> SBAR -> STAGEB 2 tiles -> 2 TILEs.
// Two independent blocks per CU cover each other's sync stalls (m114 mechanism).
__launch_bounds__(256, 2)
__global__ void k_gemm(const unsigned short* __restrict__ xb,
                       const unsigned short* __restrict__ eb,
                       unsigned* pout /* aliases d_out */) {
    extern __shared__ char smem[];

    const int tid = threadIdx.x;
    const int w = tid >> 6, l = tid & 63;
    const int lg = l >> 4, lr = l & 15, lr7 = lr & 7;
    const int bid = blockIdx.x;
    const int q = bid >> 3;
    const int panel = (bid & 7) * 4 + (q >> 4);       // XCD x owns panels 4x..4x+3
    const int split = q & 15;
    const int n0 = panel * 256, c0 = split * 512;

    // ---- staging lane constants: thread t covers chunk c = g*256 + t ----
    // row' = c>>5 = g*8 + (t>>5); p = t&31; logical chunk = (p&24)|((p&7)^(row'&7))
    const int lchk = (tid & 24) | ((tid & 7) ^ ((tid >> 5) & 7));
    const char* baseA = (const char*)xb + (size_t)(n0 + (tid >> 5)) * 512 + lchk * 16;
    const char* baseB = (const char*)eb + (size_t)(c0 + (tid >> 5)) * 512 + lchk * 16;
    const int wl16 = w * 1024;                 // wave-uniform LDS base

#define STAGE_AROUND(r) do { _Pragma("unroll") for (int g_ = 0; g_ < 16; ++g_)             \
    GLOAD_LDS(baseA + (r) * 65536 + g_ * 4096, smem + g_ * 4096 + wl16); } while (0)
#define STAGEB(t) do { _Pragma("unroll") for (int g_ = 0; g_ < 2; ++g_)                    \
    GLOAD_LDS(baseB + (size_t)(t) * 8192 + g_ * 4096,                                      \
              smem + ((t) & 7) * 8192 + g_ * 4096 + wl16); } while (0)

    // ---- A fragments: 64 rows x 256 K per wave = 128 VGPR ----
    bf16x8 aF[4][8];
#define READA() do { _Pragma("unroll") for (int mi_ = 0; mi_ < 4; ++mi_)                   \
    _Pragma("unroll") for (int kk_ = 0; kk_ < 8; ++kk_) {                                  \
        const int lc_ = kk_ * 4 + lg;                                                      \
        const int ph_ = (lc_ & 24) | ((lc_ & 7) ^ lr7);                                    \
        aF[mi_][kk_] = *reinterpret_cast<const bf16x8*>(                                   \
            smem + ((w & 1) * 64 + mi_ * 16 + lr) * 512 + ph_ * 16); } } while (0)

    // ---- prologue: A rows 0-127 (waves 0,1) then 128-255 (waves 2,3) ----
    STAGE_AROUND(0);
    WAIT_VM(0); SBAR;
    if (w < 2) READA();
    WAIT_LGKM(0); SBAR;                       // readers drained before overwrite
    STAGE_AROUND(1);
    WAIT_VM(0); SBAR;
    if (w >= 2) READA();
    WAIT_LGKM(0); SBAR;
    STAGEB(0); STAGEB(1); STAGEB(2); STAGEB(3); STAGEB(4); STAGEB(5);   // 12 loads in flight

    // ---- main loop state ----
    const f32x4 zf4 = {0.f, 0.f, 0.f, 0.f};
    unsigned rk1[16], rk2[16];
    #pragma unroll
    for (int i = 0; i < 16; ++i) { rk1[i] = 0u; rk2[i] = 0u; }

// One 16-col tile: 8 kk x {1 ds_read_b128, 4 MFMA}; kk=0 zero-C; 2-op-key TILEEND.
#define TILE(t) do {                                                                       \
    const char* sb_ = smem + ((t) & 7) * 8192;                                             \
    f32x4 ac_[4];                                                                          \
    {                                                                                      \
        const int ph0_ = ((lg & 24) | ((lg & 7) ^ lr7)) * 16;                              \
        const bf16x8 b_ = *reinterpret_cast<const bf16x8*>(sb_ + lr * 512 + ph0_);         \
        _Pragma("unroll") for (int mi_ = 0; mi_ < 4; ++mi_)                                \
            ac_[mi_] = __builtin_amdgcn_mfma_f32_16x16x32_bf16(aF[mi_][0], b_, zf4, 0, 0, 0); \
    }                                                                                      \
    _Pragma("unroll") for (int kk_ = 1; kk_ < 8; ++kk_) {                                  \
        const int lc_ = kk_ * 4 + lg;                                                      \
        const int ph_ = ((lc_ & 24) | ((lc_ & 7) ^ lr7)) * 16;                             \
        const bf16x8 b_ = *reinterpret_cast<const bf16x8*>(sb_ + lr * 512 + ph_);          \
        _Pragma("unroll") for (int mi_ = 0; mi_ < 4; ++mi_)                                \
            ac_[mi_] = __builtin_amdgcn_mfma_f32_16x16x32_bf16(aF[mi_][kk_], b_, ac_[mi_], 0, 0, 0); \
    }                                                                                      \
    const unsigned encb_ = (unsigned)(255 - ((t) & 15) * 16) - (unsigned)lr;               \
    _Pragma("unroll") for (int mi_ = 0; mi_ < 4; ++mi_)                                    \
        _Pragma("unroll") for (int rr_ = 0; rr_ < 4; ++rr_) {                              \
            const unsigned q_ = key32(ac_[mi_][rr_], encb_);                               \
            const int i_ = mi_ * 4 + rr_;                                                  \
            const unsigned lo_ = u32min(rk1[i_], q_);                                      \
            rk1[i_] = u32max(rk1[i_], q_);                                                 \
            rk2[i_] = u32max(rk2[i_], lo_);                                                \
        }                                                                                  \
} while (0)

// flush: merge the 16 lr-lanes' running top-2, store this half's partials, reset
#define FLUSH(half) do {                                                                   \
    _Pragma("unroll") for (int i_ = 0; i_ < 16; ++i_) {                                    \
        unsigned t1_ = rk1[i_], t2_ = rk2[i_];                                             \
        _Pragma("unroll") for (int off_ = 1; off_ < 16; off_ <<= 1) {                      \
            const unsigned o1_ = __shfl_xor(t1_, off_);                                    \
            const unsigned o2_ = __shfl_xor(t2_, off_);                                    \
            const unsigned n1_ = u32max(t1_, o1_), lo_ = u32min(t1_, o1_);                 \
            t2_ = u32max(u32max(t2_, o2_), lo_);                                           \
            t1_ = n1_;                                                                     \
        }                                                                                  \
        if (lr == 0) {                                                                     \
            const int row_ = n0 + w * 64 + (i_ >> 2) * 16 + lg * 4 + (i_ & 3);             \
            uint2 o_; o_.x = t1_; o_.y = t2_;                                              \
            *reinterpret_cast<uint2*>(pout + (size_t)row_ * 256 + split * 4 + (half) * 2) = o_; \
        }                                                                                  \
        rk1[i_] = 0u; rk2[i_] = 0u;                                                        \
    }                                                                                      \
} while (0)

    // ---- 16 pairs of tiles (32 x 16-col); one WAIT_VM + SBAR per pair ----
    // vmcnt trace (per wave, 2 loads/tile): entry u: outstanding = tiles 2u..2u+5 (12)
    // -> VM(8) retires 2u,2u+1. Tail: u=14 VM(4), u=15 VM(0). FLUSH(0) stores at u=7
    // cause a bounded over-wait at u=8 (r11/r13-proven acceptable). WAR for
    // STAGEB(2u+6) into slot (2u-2)&7: all waves' tile-(2u-2) ds_reads completed
    // before their SBAR(u) (every read has an in-order MFMA consumer).
    #pragma unroll 1
    for (int u = 0; u < 16; ++u) {
        if (u < 14)      { WAIT_VM(8); }
        else if (u == 14){ WAIT_VM(4); }
        else             { WAIT_VM(0); }
        SBAR;
        if (u < 13) { STAGEB(2 * u + 6); STAGEB(2 * u + 7); }
        TILE(2 * u);
        TILE(2 * u + 1);
        if (u == 7)  FLUSH(0);                // tiles 0-15 = first 256-col half
        if (u == 15) FLUSH(1);                // second half
    }
#undef STAGE_AROUND
#undef STAGEB
#undef READA
#undef TILE
#undef FLUSH
}

// ---------- fixup: global top-4 of 64 keys -> exact f32 -> argmax + gather ----------
__global__ void k_fixup(const unsigned* pk,  // == (u32*)d_out, intentionally no restrict
                        const float* __restrict__ x, const float* __restrict__ e,
                        float* out) {
    const int row = blockIdx.x * 4 + (threadIdx.x >> 6);
    const int t   = threadIdx.x & 63;   // t<32: half-split partial holder (256 cols each)
    unsigned long long kk0 = 0ull, kk1 = 0ull;
    if (t < 32) {
        const uint2 kv = reinterpret_cast<const uint2*>(pk + (size_t)row * 256)[t];
        const int col0 = t * 256 + 255 - (int)(kv.x & 255u);
        kk0 = ((unsigned long long)(kv.x & 0xFFFFFF00u) << 32) | (unsigned)(~col0);
        const int col1 = t * 256 + 255 - (int)(kv.y & 255u);
        kk1 = ((unsigned long long)(kv.y & 0xFFFFFF00u) << 32) | (unsigned)(~col1);
    }

    int cand[4];
    #pragma unroll
    for (int p = 0; p < 4; ++p) {
        unsigned long long m = kk0 > kk1 ? kk0 : kk1;
        #pragma unroll
        for (int off = 1; off < 64; off <<= 1) {
            const unsigned long long o = __shfl_xor(m, off);
            if (o > m) m = o;
        }
        cand[p] = (int)(~(unsigned)m) & (CCNT - 1);
        if (kk0 == m) kk0 = 0ull;
        if (kk1 == m) kk1 = 0ull;
    }

    const float4 xv = *reinterpret_cast<const float4*>(x + (size_t)row * DDIM + t * 4);
    float best = -INFINITY; int bc = 0x7fffffff;
    #pragma unroll
    for (int p = 0; p < 4; ++p) {
        const int c = cand[p];
        const float4 ev = *reinterpret_cast<const float4*>(e + (size_t)c * DDIM + t * 4);
        float d  = xv.x * ev.x + xv.y * ev.y + xv.z * ev.z + xv.w * ev.w;
        float ss = ev.x * ev.x + ev.y * ev.y + ev.z * ev.z + ev.w * ev.w;
        #pragma unroll
        for (int off = 1; off < 64; off <<= 1) {
            d  += __shfl_xor(d, off);
            ss += __shfl_xor(ss, off);
        }
        const float v = d * (1.0f / fmaxf(sqrtf(ss), 1e-12f));
        if (v > best || (v == best && c < bc)) { best = v; bc = c; }
    }

    if (t == 0) out[(size_t)QROWS * DDIM + row] = (float)bc;
    const float4 qv = *reinterpret_cast<const float4*>(e + (size_t)bc * DDIM + t * 4);
    *reinterpret_cast<float4*>(out + (size_t)row * DDIM + t * 4) = qv; // overwrites this row's partials only
}

extern "C" void kernel_launch(void* const* d_in, const int* in_sizes, int n_in,
                              void* d_out, int out_size, void* d_ws, size_t ws_size,
                              hipStream_t stream) {
    const float* x = (const float*)d_in[0];
    const float* e = (const float*)d_in[1];
    float* out = (float*)d_out;
    char* ws = (char*)d_ws;

    unsigned short* xb = (unsigned short*)ws;                             // 4 MB
    unsigned short* eb = (unsigned short*)(ws + (size_t)4 * 1024 * 1024); // 4 MB

    hipFuncSetAttribute(reinterpret_cast<const void*>(k_gemm),
                        hipFuncAttributeMaxDynamicSharedMemorySize, 65536);

    k_prep<<<3072, 256, 0, stream>>>(x, xb, e, eb);
    k_gemm<<<512, 256, 65536, stream>>>(xb, eb, (unsigned*)d_out);
    k_fixup<<<QROWS / 4, 256, 0, stream>>>((const unsigned*)d_out, x, e, out);
}